// Round 10
// baseline (592.426 us; speedup 1.0000x reference)
//
#include <hip/hip_runtime.h>
#include <hip/hip_bf16.h>

#define N_NODES 50000
#define KCAP 96       // bucket capacity per row; P(deg > 96 | mean 32) ~ 1e-15
#define CSTRIDE 16    // cnt padded to one counter per 64B line: breaks TCC RMW chains
#define NPASS 4

// ---------------- helpers ----------------

__device__ __forceinline__ unsigned short f2bf_rne(float f) {
    unsigned int u = __float_as_uint(f);
    u += 0x7FFF + ((u >> 16) & 1);      // round-to-nearest-even
    return (unsigned short)(u >> 16);
}
__device__ __forceinline__ float bflo(unsigned int u) {
    return __uint_as_float(u << 16);
}
__device__ __forceinline__ float bfhi(unsigned int u) {
    return __uint_as_float(u & 0xffff0000u);
}
__device__ __forceinline__ unsigned int pk(float lo, float hi) {
    return (unsigned int)f2bf_rne(lo) | ((unsigned int)f2bf_rne(hi) << 16);
}

// ---------------- fused bucket-CSR build ----------------

__global__ void zero_cnt(int* __restrict__ cnt, int n) {   // n = N*CSTRIDE
    int i = blockIdx.x * blockDim.x + threadIdx.x;
    if (i < n) cnt[i] = 0;
}

// windowed fused build: slot reservation + ushort column placement in one pass.
__global__ void build_bucket_win(const int* __restrict__ src, const int* __restrict__ dst,
                                 int* __restrict__ cnt, unsigned short* __restrict__ colb,
                                 int nEdges, int lo, int hi) {
    int e = blockIdx.x * blockDim.x + threadIdx.x;
    if (e >= nEdges) return;
    int s = src[e], d = dst[e];
    if (s >= lo && s < hi) {
        int p = atomicAdd(&cnt[s << 4], 1);
        colb[(size_t)s * KCAP + p] = (unsigned short)d;
    }
    if (d >= lo && d < hi) {
        int p = atomicAdd(&cnt[d << 4], 1);
        colb[(size_t)d * KCAP + p] = (unsigned short)s;
    }
}

// ---------------- bf16 conversion to slice-major layout ----------------
// xbs[(s*N + r)*16 .. +16) = bf16(x[r, s*16 .. s*16+16) * rsqrt(deg[r]))
// thread per (s,r); consecutive threads = consecutive r (coalesced writes).
__global__ void convert_scale_slice(const float* __restrict__ x, const int* __restrict__ cnt,
                                    unsigned short* __restrict__ xbs) {
    long i = (long)blockIdx.x * blockDim.x + threadIdx.x;
    if (i >= 8L * N_NODES) return;
    int s = (int)(i / N_NODES);
    int r = (int)(i - (long)s * N_NODES);
    float sc = rsqrtf((float)cnt[r << 4] + 1.0f);
    const float4* xp = (const float4*)(x + (size_t)r * 128 + s * 16);
    float4 a = xp[0], b = xp[1], c = xp[2], d = xp[3];
    a.x *= sc; a.y *= sc; a.z *= sc; a.w *= sc;
    b.x *= sc; b.y *= sc; b.z *= sc; b.w *= sc;
    c.x *= sc; c.y *= sc; c.z *= sc; c.w *= sc;
    d.x *= sc; d.y *= sc; d.z *= sc; d.w *= sc;
    uint4 q0, q1;
    q0.x = pk(a.x, a.y); q0.y = pk(a.z, a.w); q0.z = pk(b.x, b.y); q0.w = pk(b.z, b.w);
    q1.x = pk(c.x, c.y); q1.y = pk(c.z, c.w); q1.z = pk(d.x, d.y); q1.w = pk(d.z, d.w);
    uint4* op = (uint4*)(xbs + (size_t)i * 16);
    op[0] = q0; op[1] = q1;
}

// ---------------- gather SpMM, F=128, slice-major bf16, XCD-pinned ----------
// slice = blockIdx.x & 7 (round-robin XCD dispatch -> slice s stays on XCD s;
// per-XCD working set 50000*32B = 1.6 MB, L2-resident).
// wave per (row, slice): 32 groups x 2 lanes, 32 neighbors in flight.
__global__ void gather_spmm128_bf(const int* __restrict__ cnt,
                                  const unsigned short* __restrict__ colb,
                                  const unsigned short* __restrict__ hb,
                                  float* __restrict__ y) {
    int s = blockIdx.x & 7;
    int r = (blockIdx.x >> 3) * 4 + (threadIdx.x >> 6);
    if (r >= N_NODES) return;
    int lane = threadIdx.x & 63;
    int g = lane >> 1;   // group 0..31
    int l2 = lane & 1;   // 16B half of the 32B slice row
    int cn = cnt[r << 4];
    const unsigned short* cb = colb + (size_t)r * KCAP;
    const unsigned short* hs = hb + (size_t)s * N_NODES * 16;
    float acc[8];
#pragma unroll
    for (int i = 0; i < 8; ++i) acc[i] = 0.f;

    for (int j = g; j < cn; j += 32) {
        int c = cb[j];
        uint4 q = ((const uint4*)(hs + (size_t)c * 16))[l2];
        acc[0] += bflo(q.x); acc[1] += bfhi(q.x);
        acc[2] += bflo(q.y); acc[3] += bfhi(q.y);
        acc[4] += bflo(q.z); acc[5] += bfhi(q.z);
        acc[6] += bflo(q.w); acc[7] += bfhi(q.w);
    }
    if (g == 0) {  // self term, once
        uint4 q = ((const uint4*)(hs + (size_t)r * 16))[l2];
        acc[0] += bflo(q.x); acc[1] += bfhi(q.x);
        acc[2] += bflo(q.y); acc[3] += bfhi(q.y);
        acc[4] += bflo(q.z); acc[5] += bfhi(q.z);
        acc[6] += bflo(q.w); acc[7] += bfhi(q.w);
    }
#pragma unroll
    for (int i = 0; i < 8; ++i) {
        acc[i] += __shfl_xor(acc[i], 2);
        acc[i] += __shfl_xor(acc[i], 4);
        acc[i] += __shfl_xor(acc[i], 8);
        acc[i] += __shfl_xor(acc[i], 16);
        acc[i] += __shfl_xor(acc[i], 32);
    }
    if (g == 0) {
        float dr = rsqrtf((float)cn + 1.0f);
        float* yp = y + (size_t)r * 128 + s * 16 + l2 * 8;
        *(float4*)(yp)     = make_float4(dr * acc[0], dr * acc[1], dr * acc[2], dr * acc[3]);
        *(float4*)(yp + 4) = make_float4(dr * acc[4], dr * acc[5], dr * acc[6], dr * acc[7]);
    }
}

// ---------------- gather SpMM, F=64, slice-major bf16, XCD-pinned -----------
// slice row = 8 feats = 16B = one uint4/lane; 64 neighbors in flight per wave.
__global__ void gather_spmm64_bf(const int* __restrict__ cnt,
                                 const unsigned short* __restrict__ colb,
                                 const unsigned short* __restrict__ hb,
                                 float* __restrict__ y) {
    int s = blockIdx.x & 7;
    int r = (blockIdx.x >> 3) * 4 + (threadIdx.x >> 6);
    if (r >= N_NODES) return;
    int lane = threadIdx.x & 63;
    int cn = cnt[r << 4];
    const unsigned short* cb = colb + (size_t)r * KCAP;
    const unsigned short* hs = hb + (size_t)s * N_NODES * 8;
    float acc[8];
#pragma unroll
    for (int i = 0; i < 8; ++i) acc[i] = 0.f;

    for (int j = lane; j < cn; j += 64) {
        int c = cb[j];
        uint4 q = *(const uint4*)(hs + (size_t)c * 8);
        acc[0] += bflo(q.x); acc[1] += bfhi(q.x);
        acc[2] += bflo(q.y); acc[3] += bfhi(q.y);
        acc[4] += bflo(q.z); acc[5] += bfhi(q.z);
        acc[6] += bflo(q.w); acc[7] += bfhi(q.w);
    }
    if (lane == 0) {  // self term
        uint4 q = *(const uint4*)(hs + (size_t)r * 8);
        acc[0] += bflo(q.x); acc[1] += bfhi(q.x);
        acc[2] += bflo(q.y); acc[3] += bfhi(q.y);
        acc[4] += bflo(q.z); acc[5] += bfhi(q.z);
        acc[6] += bflo(q.w); acc[7] += bfhi(q.w);
    }
#pragma unroll
    for (int i = 0; i < 8; ++i) {
        acc[i] += __shfl_xor(acc[i], 1);
        acc[i] += __shfl_xor(acc[i], 2);
        acc[i] += __shfl_xor(acc[i], 4);
        acc[i] += __shfl_xor(acc[i], 8);
        acc[i] += __shfl_xor(acc[i], 16);
        acc[i] += __shfl_xor(acc[i], 32);
    }
    if (lane == 0) {
        float dr = rsqrtf((float)cn + 1.0f);
        float* yp = y + (size_t)r * 64 + s * 8;
        *(float4*)(yp)     = make_float4(dr * acc[0], dr * acc[1], dr * acc[2], dr * acc[3]);
        *(float4*)(yp + 4) = make_float4(dr * acc[4], dr * acc[5], dr * acc[6], dr * acc[7]);
    }
}

// ---------------- dense layers ----------------
// Register-blocked GEMM: O = A[nrows,128] @ W[128,128], ReLU, in-place-safe.
__global__ __launch_bounds__(256, 2)
void gemm128_relu_rb(const float* A, const float* __restrict__ W, float* O, int nrows) {
    __shared__ float At[32][132];
    int t = threadIdx.x;
    int rbase = blockIdx.x * 32;
    for (int i = t; i < 1024; i += 256) {
        int rr = i >> 5;
        int kg = i & 31;
        int r = rbase + rr;
        float4 v = (r < nrows) ? ((const float4*)(A + (size_t)r * 128))[kg]
                               : make_float4(0.f, 0.f, 0.f, 0.f);
        *(float4*)&At[rr][kg * 4] = v;
    }
    __syncthreads();
    int c4 = t % 32;
    int rg = t / 32;
    float4 acc[4];
#pragma unroll
    for (int i = 0; i < 4; ++i) acc[i] = make_float4(0.f, 0.f, 0.f, 0.f);
    const float* Wp = W + c4 * 4;
#pragma unroll 8
    for (int k = 0; k < 128; ++k) {
        float4 w = *(const float4*)(Wp + (size_t)k * 128);
#pragma unroll
        for (int i = 0; i < 4; ++i) {
            float a = At[rg * 4 + i][k];
            acc[i].x = fmaf(a, w.x, acc[i].x);
            acc[i].y = fmaf(a, w.y, acc[i].y);
            acc[i].z = fmaf(a, w.z, acc[i].z);
            acc[i].w = fmaf(a, w.w, acc[i].w);
        }
    }
#pragma unroll
    for (int i = 0; i < 4; ++i) {
        int r = rbase + rg * 4 + i;
        if (r < nrows) {
            float4 v = acc[i];
            v.x = fmaxf(v.x, 0.f); v.y = fmaxf(v.y, 0.f);
            v.z = fmaxf(v.z, 0.f); v.w = fmaxf(v.w, 0.f);
            *(float4*)(O + (size_t)r * 128 + c4 * 4) = v;
        }
    }
}

// O16 slice-major: O16[(s*N + r)*8 + c%8] = bf16(rsqrt(deg[r]) * (A @ W1)[r,c])
__global__ __launch_bounds__(256, 2)
void gemm64_bf(const float* __restrict__ A, const float* __restrict__ W,
               const int* __restrict__ cnt, unsigned short* __restrict__ O16, int nrows) {
    __shared__ float At[32][132];
    int t = threadIdx.x;
    int rbase = blockIdx.x * 32;
    for (int i = t; i < 1024; i += 256) {
        int rr = i >> 5;
        int kg = i & 31;
        int r = rbase + rr;
        float4 v = (r < nrows) ? ((const float4*)(A + (size_t)r * 128))[kg]
                               : make_float4(0.f, 0.f, 0.f, 0.f);
        *(float4*)&At[rr][kg * 4] = v;
    }
    __syncthreads();
    int c4 = t % 16;   // covers cols c4*4 .. c4*4+4
    int rg = t / 16;
    float4 acc[2];
#pragma unroll
    for (int i = 0; i < 2; ++i) acc[i] = make_float4(0.f, 0.f, 0.f, 0.f);
    const float* Wp = W + c4 * 4;
#pragma unroll 8
    for (int k = 0; k < 128; ++k) {
        float4 w = *(const float4*)(Wp + (size_t)k * 64);
#pragma unroll
        for (int i = 0; i < 2; ++i) {
            float a = At[rg * 2 + i][k];
            acc[i].x = fmaf(a, w.x, acc[i].x);
            acc[i].y = fmaf(a, w.y, acc[i].y);
            acc[i].z = fmaf(a, w.z, acc[i].z);
            acc[i].w = fmaf(a, w.w, acc[i].w);
        }
    }
    int s = c4 >> 1;            // slice of these 4 cols
    int o = (c4 & 1) * 4;       // offset within slice
#pragma unroll
    for (int i = 0; i < 2; ++i) {
        int r = rbase + rg * 2 + i;
        if (r < nrows) {
            float sc = rsqrtf((float)cnt[r << 4] + 1.0f);
            uint2 ov;
            ov.x = pk(acc[i].x * sc, acc[i].y * sc);
            ov.y = pk(acc[i].z * sc, acc[i].w * sc);
            *(uint2*)(O16 + ((size_t)s * N_NODES + r) * 8 + o) = ov;
        }
    }
}

// ---------------- launch ----------------

extern "C" void kernel_launch(void* const* d_in, const int* in_sizes, int n_in,
                              void* d_out, int out_size, void* d_ws, size_t ws_size,
                              hipStream_t stream) {
    const float* x  = (const float*)d_in[0];
    const float* W0 = (const float*)d_in[1];
    const float* W1 = (const float*)d_in[2];
    const int* edge = (const int*)d_in[3];
    const int E = in_sizes[3] / 2;
    const int N = N_NODES;
    const int* src = edge;
    const int* dst = edge + E;

    auto align256 = [](size_t v) { return (v + 255) & ~(size_t)255; };
    char* ws = (char*)d_ws;
    size_t off = 0;
    int* cnt = (int*)(ws + off);       off += align256((size_t)N * CSTRIDE * 4);  // 3.2 MB
    unsigned short* colb = (unsigned short*)(ws + off);
    off += align256((size_t)N * KCAP * 2);                                        // 9.6 MB
    float* bufA = (float*)(ws + off);  off += align256((size_t)N * 128 * 4);      // 25.6 MB
    unsigned short* xb16 = (unsigned short*)(ws + off);                           // slice-major N x 128 bf16
    unsigned short* b16  = (unsigned short*)(ws + off);                           // slice-major N x 64 bf16 (aliases xb16)
    off += align256((size_t)N * 128 * 2);                                         // 12.8 MB; total ~51.2 MB

    float* out = (float*)d_out;

    // fused bucket-CSR build
    zero_cnt<<<(N * CSTRIDE + 255) / 256, 256, 0, stream>>>(cnt, N * CSTRIDE);
    const int win = (N + NPASS - 1) / NPASS;
    for (int p = 0; p < NPASS; ++p) {
        int lo = p * win;
        int hi = lo + win; if (hi > N) hi = N;
        build_bucket_win<<<(E + 255) / 256, 256, 0, stream>>>(src, dst, cnt, colb, E, lo, hi);
    }

    const int spmm_blocks = 8 * ((N + 3) / 4);   // (slice, 4-row chunk) per block
    const int gemm_blocks = (N + 31) / 32;

    // x -> slice-major bf16, pre-scaled by rsqrt(deg)
    long nt = 8L * N;
    convert_scale_slice<<<(int)((nt + 255) / 256), 256, 0, stream>>>(x, cnt, xb16);

    // layer 1: bufA = Â x ; bufA = relu(bufA @ W0)
    gather_spmm128_bf<<<spmm_blocks, 256, 0, stream>>>(cnt, colb, xb16, bufA);
    gemm128_relu_rb<<<gemm_blocks, 256, 0, stream>>>(bufA, W0, bufA, N);

    // layer 2: b16 = slice-major bf16(dinv * (bufA @ W1)) ; out = Â b16
    gemm64_bf<<<gemm_blocks, 256, 0, stream>>>(bufA, W1, cnt, b16, N);
    gather_spmm64_bf<<<spmm_blocks, 256, 0, stream>>>(cnt, colb, b16, out);
}

// Round 11
// 306.216 us; speedup vs baseline: 1.9347x; 1.9347x over previous
//
#include <hip/hip_runtime.h>
#include <hip/hip_bf16.h>

#define N_NODES 50000
#define KCAP 96       // bucket capacity per row; P(deg > 96 | mean 32) ~ 1e-15
#define CSTRIDE 16    // cnt padded to one counter per 64B line: breaks TCC RMW chains
#define NPASS 4

// ---------------- helpers ----------------

__device__ __forceinline__ unsigned short f2bf_rne(float f) {
    unsigned int u = __float_as_uint(f);
    u += 0x7FFF + ((u >> 16) & 1);      // round-to-nearest-even
    return (unsigned short)(u >> 16);
}
__device__ __forceinline__ float bflo(unsigned int u) {
    return __uint_as_float(u << 16);
}
__device__ __forceinline__ float bfhi(unsigned int u) {
    return __uint_as_float(u & 0xffff0000u);
}

// ---------------- fused bucket-CSR build ----------------

__global__ void zero_cnt(int* __restrict__ cnt, int n) {   // n = N*CSTRIDE
    int i = blockIdx.x * blockDim.x + threadIdx.x;
    if (i < n) cnt[i] = 0;
}

// windowed fused build: slot reservation + ushort column placement in one pass.
__global__ void build_bucket_win(const int* __restrict__ src, const int* __restrict__ dst,
                                 int* __restrict__ cnt, unsigned short* __restrict__ colb,
                                 int nEdges, int lo, int hi) {
    int e = blockIdx.x * blockDim.x + threadIdx.x;
    if (e >= nEdges) return;
    int s = src[e], d = dst[e];
    if (s >= lo && s < hi) {
        int p = atomicAdd(&cnt[s << 4], 1);
        colb[(size_t)s * KCAP + p] = (unsigned short)d;
    }
    if (d >= lo && d < hi) {
        int p = atomicAdd(&cnt[d << 4], 1);
        colb[(size_t)d * KCAP + p] = (unsigned short)s;
    }
}

// ---------------- bf16 conversion (pre-scaled by rsqrt(deg)) ----------------

__global__ void convert_scale_bf16(const float* __restrict__ x, const int* __restrict__ cnt,
                                   unsigned short* __restrict__ xb) {
    long i = (long)blockIdx.x * blockDim.x + threadIdx.x;
    if (i >= (long)N_NODES * 32) return;
    int r = (int)(i >> 5);
    float s = rsqrtf((float)cnt[r << 4] + 1.0f);
    float4 v = ((const float4*)x)[i];
    ushort4 o;
    o.x = f2bf_rne(v.x * s); o.y = f2bf_rne(v.y * s);
    o.z = f2bf_rne(v.z * s); o.w = f2bf_rne(v.w * s);
    ((ushort4*)xb)[i] = o;
}

// ---------------- gather SpMM, F=128, bf16 pre-scaled input ----------------
// y[r] = dinv[r] * sum_{c in nbrs(r) U {r}} xb[c]
// wave = 4 groups x 16 lanes; each group loads a full 256B row (uint4/lane);
// unroll x4 -> 16 neighbor rows in flight per wave (MLP is the limiter).
__global__ void gather_spmm128_bf(const int* __restrict__ cnt,
                                  const unsigned short* __restrict__ colb,
                                  const unsigned short* __restrict__ hb,
                                  float* __restrict__ y) {
    int wave = (int)((blockIdx.x * (unsigned)blockDim.x + threadIdx.x) >> 6);
    if (wave >= N_NODES) return;
    int lane = threadIdx.x & 63;
    int g = lane >> 4;    // group 0..3
    int l = lane & 15;    // covers feats [l*8, l*8+8)
    int r = wave;
    int cn = cnt[r << 4];
    const unsigned short* cb = colb + (size_t)r * KCAP;
    float acc[8];
#pragma unroll
    for (int i = 0; i < 8; ++i) acc[i] = 0.f;

    int j = g;
    for (; j + 12 < cn; j += 16) {
        int c0 = cb[j];
        int c1 = cb[j + 4];
        int c2 = cb[j + 8];
        int c3 = cb[j + 12];
        uint4 q0 = ((const uint4*)(hb + (size_t)c0 * 128))[l];
        uint4 q1 = ((const uint4*)(hb + (size_t)c1 * 128))[l];
        uint4 q2 = ((const uint4*)(hb + (size_t)c2 * 128))[l];
        uint4 q3 = ((const uint4*)(hb + (size_t)c3 * 128))[l];
        acc[0] += bflo(q0.x); acc[1] += bfhi(q0.x);
        acc[2] += bflo(q0.y); acc[3] += bfhi(q0.y);
        acc[4] += bflo(q0.z); acc[5] += bfhi(q0.z);
        acc[6] += bflo(q0.w); acc[7] += bfhi(q0.w);
        acc[0] += bflo(q1.x); acc[1] += bfhi(q1.x);
        acc[2] += bflo(q1.y); acc[3] += bfhi(q1.y);
        acc[4] += bflo(q1.z); acc[5] += bfhi(q1.z);
        acc[6] += bflo(q1.w); acc[7] += bfhi(q1.w);
        acc[0] += bflo(q2.x); acc[1] += bfhi(q2.x);
        acc[2] += bflo(q2.y); acc[3] += bfhi(q2.y);
        acc[4] += bflo(q2.z); acc[5] += bfhi(q2.z);
        acc[6] += bflo(q2.w); acc[7] += bfhi(q2.w);
        acc[0] += bflo(q3.x); acc[1] += bfhi(q3.x);
        acc[2] += bflo(q3.y); acc[3] += bfhi(q3.y);
        acc[4] += bflo(q3.z); acc[5] += bfhi(q3.z);
        acc[6] += bflo(q3.w); acc[7] += bfhi(q3.w);
    }
    for (; j < cn; j += 4) {
        int c0 = cb[j];
        uint4 q0 = ((const uint4*)(hb + (size_t)c0 * 128))[l];
        acc[0] += bflo(q0.x); acc[1] += bfhi(q0.x);
        acc[2] += bflo(q0.y); acc[3] += bfhi(q0.y);
        acc[4] += bflo(q0.z); acc[5] += bfhi(q0.z);
        acc[6] += bflo(q0.w); acc[7] += bfhi(q0.w);
    }
    if (g == 0) {  // self term
        uint4 qs = ((const uint4*)(hb + (size_t)r * 128))[l];
        acc[0] += bflo(qs.x); acc[1] += bfhi(qs.x);
        acc[2] += bflo(qs.y); acc[3] += bfhi(qs.y);
        acc[4] += bflo(qs.z); acc[5] += bfhi(qs.z);
        acc[6] += bflo(qs.w); acc[7] += bfhi(qs.w);
    }
#pragma unroll
    for (int i = 0; i < 8; ++i) {
        acc[i] += __shfl_xor(acc[i], 16);
        acc[i] += __shfl_xor(acc[i], 32);
    }
    if (g == 0) {
        float dr = rsqrtf((float)cn + 1.0f);
        float4 o0 = make_float4(dr * acc[0], dr * acc[1], dr * acc[2], dr * acc[3]);
        float4 o1 = make_float4(dr * acc[4], dr * acc[5], dr * acc[6], dr * acc[7]);
        *(float4*)(y + (size_t)r * 128 + l * 8)     = o0;
        *(float4*)(y + (size_t)r * 128 + l * 8 + 4) = o1;
    }
}

// ---------------- gather SpMM, F=64, bf16 pre-scaled input ----------------
// wave = 8 groups x 8 lanes; each group loads a full 128B row (uint4/lane);
// unroll x2 -> 16 neighbor rows in flight per wave.
__global__ void gather_spmm64_bf(const int* __restrict__ cnt,
                                 const unsigned short* __restrict__ colb,
                                 const unsigned short* __restrict__ hb,
                                 float* __restrict__ y) {
    int wave = (int)((blockIdx.x * (unsigned)blockDim.x + threadIdx.x) >> 6);
    if (wave >= N_NODES) return;
    int lane = threadIdx.x & 63;
    int g = lane >> 3;   // group 0..7
    int l = lane & 7;    // covers feats [l*8, l*8+8)
    int r = wave;
    int cn = cnt[r << 4];
    const unsigned short* cb = colb + (size_t)r * KCAP;
    float acc[8];
#pragma unroll
    for (int i = 0; i < 8; ++i) acc[i] = 0.f;

    int j = g;
    for (; j + 8 < cn; j += 16) {
        int c0 = cb[j];
        int c1 = cb[j + 8];
        uint4 q0 = ((const uint4*)(hb + (size_t)c0 * 64))[l];
        uint4 q1 = ((const uint4*)(hb + (size_t)c1 * 64))[l];
        acc[0] += bflo(q0.x); acc[1] += bfhi(q0.x);
        acc[2] += bflo(q0.y); acc[3] += bfhi(q0.y);
        acc[4] += bflo(q0.z); acc[5] += bfhi(q0.z);
        acc[6] += bflo(q0.w); acc[7] += bfhi(q0.w);
        acc[0] += bflo(q1.x); acc[1] += bfhi(q1.x);
        acc[2] += bflo(q1.y); acc[3] += bfhi(q1.y);
        acc[4] += bflo(q1.z); acc[5] += bfhi(q1.z);
        acc[6] += bflo(q1.w); acc[7] += bfhi(q1.w);
    }
    if (j < cn) {
        int c0 = cb[j];
        uint4 q0 = ((const uint4*)(hb + (size_t)c0 * 64))[l];
        acc[0] += bflo(q0.x); acc[1] += bfhi(q0.x);
        acc[2] += bflo(q0.y); acc[3] += bfhi(q0.y);
        acc[4] += bflo(q0.z); acc[5] += bfhi(q0.z);
        acc[6] += bflo(q0.w); acc[7] += bfhi(q0.w);
    }
    if (g == 0) {  // self term
        uint4 q = ((const uint4*)(hb + (size_t)r * 64))[l];
        acc[0] += bflo(q.x); acc[1] += bfhi(q.x);
        acc[2] += bflo(q.y); acc[3] += bfhi(q.y);
        acc[4] += bflo(q.z); acc[5] += bfhi(q.z);
        acc[6] += bflo(q.w); acc[7] += bfhi(q.w);
    }
#pragma unroll
    for (int i = 0; i < 8; ++i) {
        acc[i] += __shfl_xor(acc[i], 8);
        acc[i] += __shfl_xor(acc[i], 16);
        acc[i] += __shfl_xor(acc[i], 32);
    }
    if (g == 0) {
        float dr = rsqrtf((float)cn + 1.0f);
        float4 o0 = make_float4(dr * acc[0], dr * acc[1], dr * acc[2], dr * acc[3]);
        float4 o1 = make_float4(dr * acc[4], dr * acc[5], dr * acc[6], dr * acc[7]);
        *(float4*)(y + (size_t)r * 64 + l * 8)     = o0;
        *(float4*)(y + (size_t)r * 64 + l * 8 + 4) = o1;
    }
}

// ---------------- dense layers ----------------
// Register-blocked GEMM: O = A[nrows,128] @ W[128,128], ReLU, in-place-safe.
__global__ __launch_bounds__(256, 2)
void gemm128_relu_rb(const float* A, const float* __restrict__ W, float* O, int nrows) {
    __shared__ float At[32][132];
    int t = threadIdx.x;
    int rbase = blockIdx.x * 32;
    for (int i = t; i < 1024; i += 256) {
        int rr = i >> 5;
        int kg = i & 31;
        int r = rbase + rr;
        float4 v = (r < nrows) ? ((const float4*)(A + (size_t)r * 128))[kg]
                               : make_float4(0.f, 0.f, 0.f, 0.f);
        *(float4*)&At[rr][kg * 4] = v;
    }
    __syncthreads();
    int c4 = t % 32;
    int rg = t / 32;
    float4 acc[4];
#pragma unroll
    for (int i = 0; i < 4; ++i) acc[i] = make_float4(0.f, 0.f, 0.f, 0.f);
    const float* Wp = W + c4 * 4;
#pragma unroll 8
    for (int k = 0; k < 128; ++k) {
        float4 w = *(const float4*)(Wp + (size_t)k * 128);
#pragma unroll
        for (int i = 0; i < 4; ++i) {
            float a = At[rg * 4 + i][k];
            acc[i].x = fmaf(a, w.x, acc[i].x);
            acc[i].y = fmaf(a, w.y, acc[i].y);
            acc[i].z = fmaf(a, w.z, acc[i].z);
            acc[i].w = fmaf(a, w.w, acc[i].w);
        }
    }
#pragma unroll
    for (int i = 0; i < 4; ++i) {
        int r = rbase + rg * 4 + i;
        if (r < nrows) {
            float4 v = acc[i];
            v.x = fmaxf(v.x, 0.f); v.y = fmaxf(v.y, 0.f);
            v.z = fmaxf(v.z, 0.f); v.w = fmaxf(v.w, 0.f);
            *(float4*)(O + (size_t)r * 128 + c4 * 4) = v;
        }
    }
}

// O16[nrows,64] = bf16(rsqrt(deg[r]) * (A[nrows,128] @ W[128,64]))
__global__ __launch_bounds__(256, 2)
void gemm64_bf(const float* __restrict__ A, const float* __restrict__ W,
               const int* __restrict__ cnt, unsigned short* __restrict__ O16, int nrows) {
    __shared__ float At[32][132];
    int t = threadIdx.x;
    int rbase = blockIdx.x * 32;
    for (int i = t; i < 1024; i += 256) {
        int rr = i >> 5;
        int kg = i & 31;
        int r = rbase + rr;
        float4 v = (r < nrows) ? ((const float4*)(A + (size_t)r * 128))[kg]
                               : make_float4(0.f, 0.f, 0.f, 0.f);
        *(float4*)&At[rr][kg * 4] = v;
    }
    __syncthreads();
    int c4 = t % 16;
    int rg = t / 16;
    float4 acc[2];
#pragma unroll
    for (int i = 0; i < 2; ++i) acc[i] = make_float4(0.f, 0.f, 0.f, 0.f);
    const float* Wp = W + c4 * 4;
#pragma unroll 8
    for (int k = 0; k < 128; ++k) {
        float4 w = *(const float4*)(Wp + (size_t)k * 64);
#pragma unroll
        for (int i = 0; i < 2; ++i) {
            float a = At[rg * 2 + i][k];
            acc[i].x = fmaf(a, w.x, acc[i].x);
            acc[i].y = fmaf(a, w.y, acc[i].y);
            acc[i].z = fmaf(a, w.z, acc[i].z);
            acc[i].w = fmaf(a, w.w, acc[i].w);
        }
    }
#pragma unroll
    for (int i = 0; i < 2; ++i) {
        int r = rbase + rg * 2 + i;
        if (r < nrows) {
            float s = rsqrtf((float)cnt[r << 4] + 1.0f);
            ushort4 o;
            o.x = f2bf_rne(acc[i].x * s); o.y = f2bf_rne(acc[i].y * s);
            o.z = f2bf_rne(acc[i].z * s); o.w = f2bf_rne(acc[i].w * s);
            *(ushort4*)(O16 + (size_t)r * 64 + c4 * 4) = o;
        }
    }
}

// ---------------- launch ----------------

extern "C" void kernel_launch(void* const* d_in, const int* in_sizes, int n_in,
                              void* d_out, int out_size, void* d_ws, size_t ws_size,
                              hipStream_t stream) {
    const float* x  = (const float*)d_in[0];
    const float* W0 = (const float*)d_in[1];
    const float* W1 = (const float*)d_in[2];
    const int* edge = (const int*)d_in[3];
    const int E = in_sizes[3] / 2;
    const int N = N_NODES;
    const int* src = edge;
    const int* dst = edge + E;

    auto align256 = [](size_t v) { return (v + 255) & ~(size_t)255; };
    char* ws = (char*)d_ws;
    size_t off = 0;
    int* cnt = (int*)(ws + off);       off += align256((size_t)N * CSTRIDE * 4);  // 3.2 MB
    unsigned short* colb = (unsigned short*)(ws + off);
    off += align256((size_t)N * KCAP * 2);                                        // 9.6 MB
    float* bufA = (float*)(ws + off);  off += align256((size_t)N * 128 * 4);      // 25.6 MB
    unsigned short* xb16 = (unsigned short*)(ws + off);                           // N x 128 bf16
    unsigned short* b16  = (unsigned short*)(ws + off);                           // N x 64 bf16 (aliases xb16)
    off += align256((size_t)N * 128 * 2);                                         // 12.8 MB; total ~51.2 MB

    float* out = (float*)d_out;

    // fused bucket-CSR build (padded counters)
    zero_cnt<<<(N * CSTRIDE + 255) / 256, 256, 0, stream>>>(cnt, N * CSTRIDE);
    const int win = (N + NPASS - 1) / NPASS;
    for (int p = 0; p < NPASS; ++p) {
        int lo = p * win;
        int hi = lo + win; if (hi > N) hi = N;
        build_bucket_win<<<(E + 255) / 256, 256, 0, stream>>>(src, dst, cnt, colb, E, lo, hi);
    }

    const int spmm_blocks = (N * 64 + 255) / 256;
    const int gemm_blocks = (N + 31) / 32;

    // x -> bf16, pre-scaled by rsqrt(deg)
    long n4 = (long)N * 32;
    convert_scale_bf16<<<(int)((n4 + 255) / 256), 256, 0, stream>>>(x, cnt, xb16);

    // layer 1: bufA = Â x  (via pre-scaled gather) ; bufA = relu(bufA @ W0)
    gather_spmm128_bf<<<spmm_blocks, 256, 0, stream>>>(cnt, colb, xb16, bufA);
    gemm128_relu_rb<<<gemm_blocks, 256, 0, stream>>>(bufA, W0, bufA, N);

    // layer 2: b16 = bf16(dinv * (bufA @ W1)) ; out = Â b16  (pre-scaled gather)
    gemm64_bf<<<gemm_blocks, 256, 0, stream>>>(bufA, W1, cnt, b16, N);
    gather_spmm64_bf<<<spmm_blocks, 256, 0, stream>>>(cnt, colb, b16, out);
}

// Round 12
// 269.132 us; speedup vs baseline: 2.2012x; 1.1378x over previous
//
#include <hip/hip_runtime.h>
#include <hip/hip_bf16.h>

#define N_NODES 50000
#define NPAD 50048    // 782 blocks x 64 rows for the MFMA MLP
#define KCAP 96       // bucket capacity per row; P(deg > 96 | mean 32) ~ 1e-15
#define CSTRIDE 16    // cnt padded to one counter per 64B line: breaks TCC RMW chains
#define NPASS 4

typedef short v8s __attribute__((ext_vector_type(8)));
typedef float v4f __attribute__((ext_vector_type(4)));

// ---------------- helpers ----------------

__device__ __forceinline__ unsigned short f2bf_rne(float f) {
    unsigned int u = __float_as_uint(f);
    u += 0x7FFF + ((u >> 16) & 1);      // round-to-nearest-even
    return (unsigned short)(u >> 16);
}
__device__ __forceinline__ float bflo(unsigned int u) {
    return __uint_as_float(u << 16);
}
__device__ __forceinline__ float bfhi(unsigned int u) {
    return __uint_as_float(u & 0xffff0000u);
}
__device__ __forceinline__ unsigned int pk(float lo, float hi) {
    return (unsigned int)f2bf_rne(lo) | ((unsigned int)f2bf_rne(hi) << 16);
}

// ---------------- fused bucket-CSR build ----------------

__global__ void zero_cnt(int* __restrict__ cnt, int n) {   // n = N*CSTRIDE
    int i = blockIdx.x * blockDim.x + threadIdx.x;
    if (i < n) cnt[i] = 0;
}

__global__ void build_bucket_win(const int* __restrict__ src, const int* __restrict__ dst,
                                 int* __restrict__ cnt, unsigned short* __restrict__ colb,
                                 int nEdges, int lo, int hi) {
    int e = blockIdx.x * blockDim.x + threadIdx.x;
    if (e >= nEdges) return;
    int s = src[e], d = dst[e];
    if (s >= lo && s < hi) {
        int p = atomicAdd(&cnt[s << 4], 1);
        colb[(size_t)s * KCAP + p] = (unsigned short)d;
    }
    if (d >= lo && d < hi) {
        int p = atomicAdd(&cnt[d << 4], 1);
        colb[(size_t)d * KCAP + p] = (unsigned short)s;
    }
}

// ---------------- weight transpose + bf16 cast ----------------
// W0t[n][k] = bf16(W0[k][n]) (128x128); W1t[n][k] = bf16(W1[k][n]) (64x128)
__global__ void transpose_wb(const float* __restrict__ W0, const float* __restrict__ W1,
                             unsigned short* __restrict__ W0t, unsigned short* __restrict__ W1t) {
    int i = blockIdx.x * blockDim.x + threadIdx.x;
    if (i < 2048) {
        int n = i >> 4, kc = i & 15;
        unsigned short tmp[8];
#pragma unroll
        for (int j = 0; j < 8; ++j) tmp[j] = f2bf_rne(W0[(kc * 8 + j) * 128 + n]);
        *(uint4*)(W0t + (size_t)n * 128 + kc * 8) = *(uint4*)tmp;
    } else if (i < 3072) {
        int ii = i - 2048;
        int n = ii >> 4, kc = ii & 15;
        unsigned short tmp[8];
#pragma unroll
        for (int j = 0; j < 8; ++j) tmp[j] = f2bf_rne(W1[(kc * 8 + j) * 64 + n]);
        *(uint4*)(W1t + (size_t)n * 128 + kc * 8) = *(uint4*)tmp;
    }
}

__global__ void zero_pad16(unsigned short* __restrict__ p, int n8) {  // n8 uint4 chunks
    int i = blockIdx.x * blockDim.x + threadIdx.x;
    if (i < n8) ((uint4*)p)[i] = make_uint4(0, 0, 0, 0);
}

// ---------------- bf16 conversion (pre-scaled by rsqrt(deg)) ----------------

__global__ void convert_scale_bf16(const float* __restrict__ x, const int* __restrict__ cnt,
                                   unsigned short* __restrict__ xb) {
    long i = (long)blockIdx.x * blockDim.x + threadIdx.x;
    if (i >= (long)N_NODES * 32) return;
    int r = (int)(i >> 5);
    float s = rsqrtf((float)cnt[r << 4] + 1.0f);
    float4 v = ((const float4*)x)[i];
    ushort4 o;
    o.x = f2bf_rne(v.x * s); o.y = f2bf_rne(v.y * s);
    o.z = f2bf_rne(v.z * s); o.w = f2bf_rne(v.w * s);
    ((ushort4*)xb)[i] = o;
}

// ---------------- gather SpMM, F=128, bf16 in, bf16 out ----------------
// y1b[r] = bf16( dinv[r] * sum_{c in nbrs(r) U {r}} xb[c] )
__global__ void gather_spmm128_bf(const int* __restrict__ cnt,
                                  const unsigned short* __restrict__ colb,
                                  const unsigned short* __restrict__ hb,
                                  unsigned short* __restrict__ y1b) {
    int wave = (int)((blockIdx.x * (unsigned)blockDim.x + threadIdx.x) >> 6);
    if (wave >= N_NODES) return;
    int lane = threadIdx.x & 63;
    int g = lane >> 4;    // group 0..3
    int l = lane & 15;    // covers feats [l*8, l*8+8)
    int r = wave;
    int cn = cnt[r << 4];
    const unsigned short* cb = colb + (size_t)r * KCAP;
    float acc[8];
#pragma unroll
    for (int i = 0; i < 8; ++i) acc[i] = 0.f;

    int j = g;
    for (; j + 12 < cn; j += 16) {
        int c0 = cb[j];
        int c1 = cb[j + 4];
        int c2 = cb[j + 8];
        int c3 = cb[j + 12];
        uint4 q0 = ((const uint4*)(hb + (size_t)c0 * 128))[l];
        uint4 q1 = ((const uint4*)(hb + (size_t)c1 * 128))[l];
        uint4 q2 = ((const uint4*)(hb + (size_t)c2 * 128))[l];
        uint4 q3 = ((const uint4*)(hb + (size_t)c3 * 128))[l];
        acc[0] += bflo(q0.x); acc[1] += bfhi(q0.x);
        acc[2] += bflo(q0.y); acc[3] += bfhi(q0.y);
        acc[4] += bflo(q0.z); acc[5] += bfhi(q0.z);
        acc[6] += bflo(q0.w); acc[7] += bfhi(q0.w);
        acc[0] += bflo(q1.x); acc[1] += bfhi(q1.x);
        acc[2] += bflo(q1.y); acc[3] += bfhi(q1.y);
        acc[4] += bflo(q1.z); acc[5] += bfhi(q1.z);
        acc[6] += bflo(q1.w); acc[7] += bfhi(q1.w);
        acc[0] += bflo(q2.x); acc[1] += bfhi(q2.x);
        acc[2] += bflo(q2.y); acc[3] += bfhi(q2.y);
        acc[4] += bflo(q2.z); acc[5] += bfhi(q2.z);
        acc[6] += bflo(q2.w); acc[7] += bfhi(q2.w);
        acc[0] += bflo(q3.x); acc[1] += bfhi(q3.x);
        acc[2] += bflo(q3.y); acc[3] += bfhi(q3.y);
        acc[4] += bflo(q3.z); acc[5] += bfhi(q3.z);
        acc[6] += bflo(q3.w); acc[7] += bfhi(q3.w);
    }
    for (; j < cn; j += 4) {
        int c0 = cb[j];
        uint4 q0 = ((const uint4*)(hb + (size_t)c0 * 128))[l];
        acc[0] += bflo(q0.x); acc[1] += bfhi(q0.x);
        acc[2] += bflo(q0.y); acc[3] += bfhi(q0.y);
        acc[4] += bflo(q0.z); acc[5] += bfhi(q0.z);
        acc[6] += bflo(q0.w); acc[7] += bfhi(q0.w);
    }
    if (g == 0) {  // self term
        uint4 qs = ((const uint4*)(hb + (size_t)r * 128))[l];
        acc[0] += bflo(qs.x); acc[1] += bfhi(qs.x);
        acc[2] += bflo(qs.y); acc[3] += bfhi(qs.y);
        acc[4] += bflo(qs.z); acc[5] += bfhi(qs.z);
        acc[6] += bflo(qs.w); acc[7] += bfhi(qs.w);
    }
#pragma unroll
    for (int i = 0; i < 8; ++i) {
        acc[i] += __shfl_xor(acc[i], 16);
        acc[i] += __shfl_xor(acc[i], 32);
    }
    if (g == 0) {
        float dr = rsqrtf((float)cn + 1.0f);
        uint4 o;
        o.x = pk(dr * acc[0], dr * acc[1]);
        o.y = pk(dr * acc[2], dr * acc[3]);
        o.z = pk(dr * acc[4], dr * acc[5]);
        o.w = pk(dr * acc[6], dr * acc[7]);
        *(uint4*)(y1b + (size_t)r * 128 + l * 8) = o;
    }
}

// ---------------- gather SpMM, F=64, bf16 pre-scaled input ----------------
__global__ void gather_spmm64_bf(const int* __restrict__ cnt,
                                 const unsigned short* __restrict__ colb,
                                 const unsigned short* __restrict__ hb,
                                 float* __restrict__ y) {
    int wave = (int)((blockIdx.x * (unsigned)blockDim.x + threadIdx.x) >> 6);
    if (wave >= N_NODES) return;
    int lane = threadIdx.x & 63;
    int g = lane >> 3;   // group 0..7
    int l = lane & 7;    // covers feats [l*8, l*8+8)
    int r = wave;
    int cn = cnt[r << 4];
    const unsigned short* cb = colb + (size_t)r * KCAP;
    float acc[8];
#pragma unroll
    for (int i = 0; i < 8; ++i) acc[i] = 0.f;

    int j = g;
    for (; j + 8 < cn; j += 16) {
        int c0 = cb[j];
        int c1 = cb[j + 8];
        uint4 q0 = ((const uint4*)(hb + (size_t)c0 * 64))[l];
        uint4 q1 = ((const uint4*)(hb + (size_t)c1 * 64))[l];
        acc[0] += bflo(q0.x); acc[1] += bfhi(q0.x);
        acc[2] += bflo(q0.y); acc[3] += bfhi(q0.y);
        acc[4] += bflo(q0.z); acc[5] += bfhi(q0.z);
        acc[6] += bflo(q0.w); acc[7] += bfhi(q0.w);
        acc[0] += bflo(q1.x); acc[1] += bfhi(q1.x);
        acc[2] += bflo(q1.y); acc[3] += bfhi(q1.y);
        acc[4] += bflo(q1.z); acc[5] += bfhi(q1.z);
        acc[6] += bflo(q1.w); acc[7] += bfhi(q1.w);
    }
    if (j < cn) {
        int c0 = cb[j];
        uint4 q0 = ((const uint4*)(hb + (size_t)c0 * 64))[l];
        acc[0] += bflo(q0.x); acc[1] += bfhi(q0.x);
        acc[2] += bflo(q0.y); acc[3] += bfhi(q0.y);
        acc[4] += bflo(q0.z); acc[5] += bfhi(q0.z);
        acc[6] += bflo(q0.w); acc[7] += bfhi(q0.w);
    }
    if (g == 0) {  // self term
        uint4 q = ((const uint4*)(hb + (size_t)r * 64))[l];
        acc[0] += bflo(q.x); acc[1] += bfhi(q.x);
        acc[2] += bflo(q.y); acc[3] += bfhi(q.y);
        acc[4] += bflo(q.z); acc[5] += bfhi(q.z);
        acc[6] += bflo(q.w); acc[7] += bfhi(q.w);
    }
#pragma unroll
    for (int i = 0; i < 8; ++i) {
        acc[i] += __shfl_xor(acc[i], 8);
        acc[i] += __shfl_xor(acc[i], 16);
        acc[i] += __shfl_xor(acc[i], 32);
    }
    if (g == 0) {
        float dr = rsqrtf((float)cn + 1.0f);
        float4 o0 = make_float4(dr * acc[0], dr * acc[1], dr * acc[2], dr * acc[3]);
        float4 o1 = make_float4(dr * acc[4], dr * acc[5], dr * acc[6], dr * acc[7]);
        *(float4*)(y + (size_t)r * 64 + l * 8)     = o0;
        *(float4*)(y + (size_t)r * 64 + l * 8 + 4) = o1;
    }
}

// ---------------- fused MFMA MLP: b16 = bf16(dinv * relu(y1 @ W0) @ W1) ------
// 64 rows/block, 4 waves; each wave computes a 16-row tile with
// v_mfma_f32_16x16x32_bf16. A-frag: A[m=lane&15][k=quad*8+j] (m120-verified);
// C/D: col=lane&15, row=quad*4+reg (m89-verified). h round-trips through
// per-wave LDS (C-layout -> A-layout), padded stride 136 ushorts.
__global__ __launch_bounds__(256, 2)
void fused_mlp_mfma(const unsigned short* __restrict__ y1b,
                    const unsigned short* __restrict__ W0t,
                    const unsigned short* __restrict__ W1t,
                    const int* __restrict__ cnt,
                    unsigned short* __restrict__ b16) {
    __shared__ __align__(16) unsigned short hl[4][16 * 136];
    int t = threadIdx.x;
    int w = t >> 6, lane = t & 63;
    int quad = lane >> 4, lm = lane & 15;
    int rbase = blockIdx.x * 64 + w * 16;
    unsigned short* h = &hl[w][0];

    // phase 1: h(16x128) = relu(A(16x128) @ W0)
    const unsigned short* arow = y1b + (size_t)(rbase + lm) * 128 + quad * 8;
    v8s af[4];
#pragma unroll
    for (int ks = 0; ks < 4; ++ks) af[ks] = *(const v8s*)(arow + ks * 32);
#pragma unroll
    for (int n0 = 0; n0 < 8; ++n0) {
        v4f acc = {0.f, 0.f, 0.f, 0.f};
        const unsigned short* wrow = W0t + (size_t)(n0 * 16 + lm) * 128 + quad * 8;
#pragma unroll
        for (int ks = 0; ks < 4; ++ks) {
            v8s bf = *(const v8s*)(wrow + ks * 32);
            acc = __builtin_amdgcn_mfma_f32_16x16x32_bf16(af[ks], bf, acc, 0, 0, 0);
        }
#pragma unroll
        for (int i = 0; i < 4; ++i)
            h[(quad * 4 + i) * 136 + n0 * 16 + lm] = f2bf_rne(fmaxf(acc[i], 0.f));
    }
    // wave-private LDS region: no __syncthreads needed (compiler orders aliasing DS ops)

    // phase 2: b(16x64) = h @ W1, scale by rsqrt(deg), store bf16
    v8s hf[4];
#pragma unroll
    for (int ks = 0; ks < 4; ++ks)
        hf[ks] = *(const v8s*)(h + lm * 136 + ks * 32 + quad * 8);
    float sc[4];
#pragma unroll
    for (int i = 0; i < 4; ++i) {
        int r = rbase + quad * 4 + i;
        sc[i] = (r < N_NODES) ? rsqrtf((float)cnt[r << 4] + 1.0f) : 0.f;
    }
#pragma unroll
    for (int n0 = 0; n0 < 4; ++n0) {
        v4f acc = {0.f, 0.f, 0.f, 0.f};
        const unsigned short* wrow = W1t + (size_t)(n0 * 16 + lm) * 128 + quad * 8;
#pragma unroll
        for (int ks = 0; ks < 4; ++ks) {
            v8s bf = *(const v8s*)(wrow + ks * 32);
            acc = __builtin_amdgcn_mfma_f32_16x16x32_bf16(hf[ks], bf, acc, 0, 0, 0);
        }
#pragma unroll
        for (int i = 0; i < 4; ++i) {
            int r = rbase + quad * 4 + i;
            if (r < N_NODES)
                b16[(size_t)r * 64 + n0 * 16 + lm] = f2bf_rne(acc[i] * sc[i]);
        }
    }
}

// ---------------- launch ----------------

extern "C" void kernel_launch(void* const* d_in, const int* in_sizes, int n_in,
                              void* d_out, int out_size, void* d_ws, size_t ws_size,
                              hipStream_t stream) {
    const float* x  = (const float*)d_in[0];
    const float* W0 = (const float*)d_in[1];
    const float* W1 = (const float*)d_in[2];
    const int* edge = (const int*)d_in[3];
    const int E = in_sizes[3] / 2;
    const int N = N_NODES;
    const int* src = edge;
    const int* dst = edge + E;

    auto align256 = [](size_t v) { return (v + 255) & ~(size_t)255; };
    char* ws = (char*)d_ws;
    size_t off = 0;
    int* cnt = (int*)(ws + off);       off += align256((size_t)N * CSTRIDE * 4);   // 3.2 MB
    unsigned short* colb = (unsigned short*)(ws + off);
    off += align256((size_t)N * KCAP * 2);                                         // 9.6 MB
    unsigned short* xb16 = (unsigned short*)(ws + off);
    off += align256((size_t)N * 128 * 2);                                          // 12.8 MB
    unsigned short* y1b = (unsigned short*)(ws + off);
    off += align256((size_t)NPAD * 128 * 2);                                       // 12.8 MB
    unsigned short* b16 = (unsigned short*)(ws + off);
    off += align256((size_t)N * 64 * 2);                                           // 6.4 MB
    unsigned short* W0t = (unsigned short*)(ws + off); off += align256(128 * 128 * 2);
    unsigned short* W1t = (unsigned short*)(ws + off); off += align256(64 * 128 * 2);
    // total ~44.9 MB

    float* out = (float*)d_out;

    // fused bucket-CSR build (padded counters)
    zero_cnt<<<(N * CSTRIDE + 255) / 256, 256, 0, stream>>>(cnt, N * CSTRIDE);
    transpose_wb<<<12, 256, 0, stream>>>(W0, W1, W0t, W1t);
    zero_pad16<<<3, 256, 0, stream>>>(y1b + (size_t)N * 128, (NPAD - N) * 128 / 8);
    const int win = (N + NPASS - 1) / NPASS;
    for (int p = 0; p < NPASS; ++p) {
        int lo = p * win;
        int hi = lo + win; if (hi > N) hi = N;
        build_bucket_win<<<(E + 255) / 256, 256, 0, stream>>>(src, dst, cnt, colb, E, lo, hi);
    }

    const int spmm_blocks = (N * 64 + 255) / 256;

    // x -> bf16, pre-scaled by rsqrt(deg)
    long n4 = (long)N * 32;
    convert_scale_bf16<<<(int)((n4 + 255) / 256), 256, 0, stream>>>(x, cnt, xb16);

    // layer 1 gather: y1b = bf16(Â x)
    gather_spmm128_bf<<<spmm_blocks, 256, 0, stream>>>(cnt, colb, xb16, y1b);

    // fused MLP (MFMA): b16 = bf16(dinv * relu(y1 @ W0) @ W1)
    fused_mlp_mfma<<<NPAD / 64, 256, 0, stream>>>(y1b, W0t, W1t, cnt, b16);

    // layer 2 gather: out = Â b16
    gather_spmm64_bf<<<spmm_blocks, 256, 0, stream>>>(cnt, colb, b16, out);
}

// Round 13
// 269.024 us; speedup vs baseline: 2.2021x; 1.0004x over previous
//
#include <hip/hip_runtime.h>
#include <hip/hip_bf16.h>

#define N_NODES 50000
#define NPAD 50048    // 782 blocks x 64 rows for the fused gather+MLP
#define KCAP 96       // bucket capacity per row; P(deg > 96 | mean 32) ~ 1e-15
#define CSTRIDE 16    // cnt padded to one counter per 64B line: breaks TCC RMW chains
#define NPASS 3       // 16667-row window -> 3.2 MB colb window, fits 4 MiB per-XCD L2

typedef short v8s __attribute__((ext_vector_type(8)));
typedef float v4f __attribute__((ext_vector_type(4)));

// ---------------- helpers ----------------

__device__ __forceinline__ unsigned short f2bf_rne(float f) {
    unsigned int u = __float_as_uint(f);
    u += 0x7FFF + ((u >> 16) & 1);      // round-to-nearest-even
    return (unsigned short)(u >> 16);
}
__device__ __forceinline__ float bflo(unsigned int u) {
    return __uint_as_float(u << 16);
}
__device__ __forceinline__ float bfhi(unsigned int u) {
    return __uint_as_float(u & 0xffff0000u);
}
__device__ __forceinline__ unsigned int pk(float lo, float hi) {
    return (unsigned int)f2bf_rne(lo) | ((unsigned int)f2bf_rne(hi) << 16);
}

// ---------------- prep: zero counters + transpose/cast weights ----------------
// W0t[n][k] = bf16(W0[k][n]) (128x128); W1t[n][k] = bf16(W1[k][n]) (64x128)
__global__ void prep(const float* __restrict__ W0, const float* __restrict__ W1,
                     int* __restrict__ cnt,
                     unsigned short* __restrict__ W0t, unsigned short* __restrict__ W1t) {
    int i = blockIdx.x * blockDim.x + threadIdx.x;
    if (i < N_NODES * CSTRIDE) { cnt[i] = 0; return; }
    int j = i - N_NODES * CSTRIDE;
    if (j < 2048) {
        int n = j >> 4, kc = j & 15;
        unsigned short tmp[8];
#pragma unroll
        for (int q = 0; q < 8; ++q) tmp[q] = f2bf_rne(W0[(kc * 8 + q) * 128 + n]);
        *(uint4*)(W0t + (size_t)n * 128 + kc * 8) = *(uint4*)tmp;
    } else if (j < 3072) {
        int jj = j - 2048;
        int n = jj >> 4, kc = jj & 15;
        unsigned short tmp[8];
#pragma unroll
        for (int q = 0; q < 8; ++q) tmp[q] = f2bf_rne(W1[(kc * 8 + q) * 64 + n]);
        *(uint4*)(W1t + (size_t)n * 128 + kc * 8) = *(uint4*)tmp;
    }
}

// ---------------- fused bucket-CSR build ----------------

__global__ void build_bucket_win(const int* __restrict__ src, const int* __restrict__ dst,
                                 int* __restrict__ cnt, unsigned short* __restrict__ colb,
                                 int nEdges, int lo, int hi) {
    int e = blockIdx.x * blockDim.x + threadIdx.x;
    if (e >= nEdges) return;
    int s = src[e], d = dst[e];
    if (s >= lo && s < hi) {
        int p = atomicAdd(&cnt[s << 4], 1);
        colb[(size_t)s * KCAP + p] = (unsigned short)d;
    }
    if (d >= lo && d < hi) {
        int p = atomicAdd(&cnt[d << 4], 1);
        colb[(size_t)d * KCAP + p] = (unsigned short)s;
    }
}

// ---------------- bf16 conversion (pre-scaled by rsqrt(deg)) ----------------

__global__ void convert_scale_bf16(const float* __restrict__ x, const int* __restrict__ cnt,
                                   unsigned short* __restrict__ xb) {
    long i = (long)blockIdx.x * blockDim.x + threadIdx.x;
    if (i >= (long)N_NODES * 32) return;
    int r = (int)(i >> 5);
    float s = rsqrtf((float)cnt[r << 4] + 1.0f);
    float4 v = ((const float4*)x)[i];
    ushort4 o;
    o.x = f2bf_rne(v.x * s); o.y = f2bf_rne(v.y * s);
    o.z = f2bf_rne(v.z * s); o.w = f2bf_rne(v.w * s);
    ((ushort4*)xb)[i] = o;
}

// ---------------- fused gather(F=128) + MFMA MLP -----------------------------
// Per wave: gather its 16-row y1 tile (bf16) into private LDS, then
// b16[r] = bf16(dinv[r] * relu(y1 @ W0) @ W1) via v_mfma_f32_16x16x32_bf16.
// A-frag: A[m=lane&15][k=quad*8+j] (m120-verified layout);
// C/D: col=lane&15, row=quad*4+reg (m89-verified).
// No __syncthreads: each wave's LDS segments are private; intra-wave DS
// ordering is handled by compiler-inserted lgkmcnt (same pattern as R12).
__global__ __launch_bounds__(256, 2)
void gather_mlp(const int* __restrict__ cnt,
                const unsigned short* __restrict__ colb,
                const unsigned short* __restrict__ xb,
                const unsigned short* __restrict__ W0t,
                const unsigned short* __restrict__ W1t,
                unsigned short* __restrict__ b16) {
    __shared__ __align__(16) unsigned short Al[4][16 * 136];  // gathered y1 tiles
    __shared__ __align__(16) unsigned short Hl[4][16 * 136];  // hidden tiles
    int t = threadIdx.x;
    int w = t >> 6, lane = t & 63;
    int g = lane >> 4, l = lane & 15;      // group / lane-in-group
    int tilebase = blockIdx.x * 64 + w * 16;
    unsigned short* A = &Al[w][0];
    unsigned short* H = &Hl[w][0];

    // ---- gather phase: group g handles rows tilebase + g + {0,4,8,12}
#pragma unroll
    for (int it = 0; it < 4; ++it) {
        int rr = g + it * 4;
        int r = tilebase + rr;
        float acc[8];
#pragma unroll
        for (int i = 0; i < 8; ++i) acc[i] = 0.f;
        float dr = 0.f;
        if (r < N_NODES) {
            int cn = cnt[r << 4];
            const unsigned short* cb = colb + (size_t)r * KCAP;
            int j = 0;
            for (; j + 3 < cn; j += 4) {
                int c0 = cb[j], c1 = cb[j + 1], c2 = cb[j + 2], c3 = cb[j + 3];
                uint4 q0 = ((const uint4*)(xb + (size_t)c0 * 128))[l];
                uint4 q1 = ((const uint4*)(xb + (size_t)c1 * 128))[l];
                uint4 q2 = ((const uint4*)(xb + (size_t)c2 * 128))[l];
                uint4 q3 = ((const uint4*)(xb + (size_t)c3 * 128))[l];
                acc[0] += bflo(q0.x); acc[1] += bfhi(q0.x);
                acc[2] += bflo(q0.y); acc[3] += bfhi(q0.y);
                acc[4] += bflo(q0.z); acc[5] += bfhi(q0.z);
                acc[6] += bflo(q0.w); acc[7] += bfhi(q0.w);
                acc[0] += bflo(q1.x); acc[1] += bfhi(q1.x);
                acc[2] += bflo(q1.y); acc[3] += bfhi(q1.y);
                acc[4] += bflo(q1.z); acc[5] += bfhi(q1.z);
                acc[6] += bflo(q1.w); acc[7] += bfhi(q1.w);
                acc[0] += bflo(q2.x); acc[1] += bfhi(q2.x);
                acc[2] += bflo(q2.y); acc[3] += bfhi(q2.y);
                acc[4] += bflo(q2.z); acc[5] += bfhi(q2.z);
                acc[6] += bflo(q2.w); acc[7] += bfhi(q2.w);
                acc[0] += bflo(q3.x); acc[1] += bfhi(q3.x);
                acc[2] += bflo(q3.y); acc[3] += bfhi(q3.y);
                acc[4] += bflo(q3.z); acc[5] += bfhi(q3.z);
                acc[6] += bflo(q3.w); acc[7] += bfhi(q3.w);
            }
            for (; j < cn; ++j) {
                int c0 = cb[j];
                uint4 q0 = ((const uint4*)(xb + (size_t)c0 * 128))[l];
                acc[0] += bflo(q0.x); acc[1] += bfhi(q0.x);
                acc[2] += bflo(q0.y); acc[3] += bfhi(q0.y);
                acc[4] += bflo(q0.z); acc[5] += bfhi(q0.z);
                acc[6] += bflo(q0.w); acc[7] += bfhi(q0.w);
            }
            // self term
            uint4 qs = ((const uint4*)(xb + (size_t)r * 128))[l];
            acc[0] += bflo(qs.x); acc[1] += bfhi(qs.x);
            acc[2] += bflo(qs.y); acc[3] += bfhi(qs.y);
            acc[4] += bflo(qs.z); acc[5] += bfhi(qs.z);
            acc[6] += bflo(qs.w); acc[7] += bfhi(qs.w);
            dr = rsqrtf((float)cn + 1.0f);
        }
        uint4 o;
        o.x = pk(dr * acc[0], dr * acc[1]);
        o.y = pk(dr * acc[2], dr * acc[3]);
        o.z = pk(dr * acc[4], dr * acc[5]);
        o.w = pk(dr * acc[6], dr * acc[7]);
        *(uint4*)(A + rr * 136 + l * 8) = o;
    }

    // ---- MLP phase (per-wave 16-row tile) ----
    int quad = g, lm = l;
    v8s af[4];
#pragma unroll
    for (int ks = 0; ks < 4; ++ks)
        af[ks] = *(const v8s*)(A + lm * 136 + ks * 32 + quad * 8);

    // phase 1: H(16x128) = relu(A @ W0)
#pragma unroll
    for (int n0 = 0; n0 < 8; ++n0) {
        v4f acc = {0.f, 0.f, 0.f, 0.f};
        const unsigned short* wrow = W0t + (size_t)(n0 * 16 + lm) * 128 + quad * 8;
#pragma unroll
        for (int ks = 0; ks < 4; ++ks) {
            v8s bf = *(const v8s*)(wrow + ks * 32);
            acc = __builtin_amdgcn_mfma_f32_16x16x32_bf16(af[ks], bf, acc, 0, 0, 0);
        }
#pragma unroll
        for (int i = 0; i < 4; ++i)
            H[(quad * 4 + i) * 136 + n0 * 16 + lm] = f2bf_rne(fmaxf(acc[i], 0.f));
    }

    // phase 2: b(16x64) = H @ W1, scale by rsqrt(deg), store bf16
    v8s hf[4];
#pragma unroll
    for (int ks = 0; ks < 4; ++ks)
        hf[ks] = *(const v8s*)(H + lm * 136 + ks * 32 + quad * 8);
    float sc[4];
#pragma unroll
    for (int i = 0; i < 4; ++i) {
        int r = tilebase + quad * 4 + i;
        sc[i] = (r < N_NODES) ? rsqrtf((float)cnt[r << 4] + 1.0f) : 0.f;
    }
#pragma unroll
    for (int n0 = 0; n0 < 4; ++n0) {
        v4f acc = {0.f, 0.f, 0.f, 0.f};
        const unsigned short* wrow = W1t + (size_t)(n0 * 16 + lm) * 128 + quad * 8;
#pragma unroll
        for (int ks = 0; ks < 4; ++ks) {
            v8s bf = *(const v8s*)(wrow + ks * 32);
            acc = __builtin_amdgcn_mfma_f32_16x16x32_bf16(hf[ks], bf, acc, 0, 0, 0);
        }
#pragma unroll
        for (int i = 0; i < 4; ++i) {
            int r = tilebase + quad * 4 + i;
            if (r < N_NODES)
                b16[(size_t)r * 64 + n0 * 16 + lm] = f2bf_rne(acc[i] * sc[i]);
        }
    }
}

// ---------------- gather SpMM, F=64, bf16 pre-scaled input ----------------
__global__ void gather_spmm64_bf(const int* __restrict__ cnt,
                                 const unsigned short* __restrict__ colb,
                                 const unsigned short* __restrict__ hb,
                                 float* __restrict__ y) {
    int wave = (int)((blockIdx.x * (unsigned)blockDim.x + threadIdx.x) >> 6);
    if (wave >= N_NODES) return;
    int lane = threadIdx.x & 63;
    int g = lane >> 3;   // group 0..7
    int l = lane & 7;    // covers feats [l*8, l*8+8)
    int r = wave;
    int cn = cnt[r << 4];
    const unsigned short* cb = colb + (size_t)r * KCAP;
    float acc[8];
#pragma unroll
    for (int i = 0; i < 8; ++i) acc[i] = 0.f;

    int j = g;
    for (; j + 8 < cn; j += 16) {
        int c0 = cb[j];
        int c1 = cb[j + 8];
        uint4 q0 = ((const uint4*)(hb + (size_t)c0 * 64))[l];
        uint4 q1 = ((const uint4*)(hb + (size_t)c1 * 64))[l];
        acc[0] += bflo(q0.x); acc[1] += bfhi(q0.x);
        acc[2] += bflo(q0.y); acc[3] += bfhi(q0.y);
        acc[4] += bflo(q0.z); acc[5] += bfhi(q0.z);
        acc[6] += bflo(q0.w); acc[7] += bfhi(q0.w);
        acc[0] += bflo(q1.x); acc[1] += bfhi(q1.x);
        acc[2] += bflo(q1.y); acc[3] += bfhi(q1.y);
        acc[4] += bflo(q1.z); acc[5] += bfhi(q1.z);
        acc[6] += bflo(q1.w); acc[7] += bfhi(q1.w);
    }
    if (j < cn) {
        int c0 = cb[j];
        uint4 q0 = ((const uint4*)(hb + (size_t)c0 * 64))[l];
        acc[0] += bflo(q0.x); acc[1] += bfhi(q0.x);
        acc[2] += bflo(q0.y); acc[3] += bfhi(q0.y);
        acc[4] += bflo(q0.z); acc[5] += bfhi(q0.z);
        acc[6] += bflo(q0.w); acc[7] += bfhi(q0.w);
    }
    if (g == 0) {  // self term
        uint4 q = ((const uint4*)(hb + (size_t)r * 64))[l];
        acc[0] += bflo(q.x); acc[1] += bfhi(q.x);
        acc[2] += bflo(q.y); acc[3] += bfhi(q.y);
        acc[4] += bflo(q.z); acc[5] += bfhi(q.z);
        acc[6] += bflo(q.w); acc[7] += bfhi(q.w);
    }
#pragma unroll
    for (int i = 0; i < 8; ++i) {
        acc[i] += __shfl_xor(acc[i], 8);
        acc[i] += __shfl_xor(acc[i], 16);
        acc[i] += __shfl_xor(acc[i], 32);
    }
    if (g == 0) {
        float dr = rsqrtf((float)cn + 1.0f);
        float4 o0 = make_float4(dr * acc[0], dr * acc[1], dr * acc[2], dr * acc[3]);
        float4 o1 = make_float4(dr * acc[4], dr * acc[5], dr * acc[6], dr * acc[7]);
        *(float4*)(y + (size_t)r * 64 + l * 8)     = o0;
        *(float4*)(y + (size_t)r * 64 + l * 8 + 4) = o1;
    }
}

// ---------------- launch ----------------

extern "C" void kernel_launch(void* const* d_in, const int* in_sizes, int n_in,
                              void* d_out, int out_size, void* d_ws, size_t ws_size,
                              hipStream_t stream) {
    const float* x  = (const float*)d_in[0];
    const float* W0 = (const float*)d_in[1];
    const float* W1 = (const float*)d_in[2];
    const int* edge = (const int*)d_in[3];
    const int E = in_sizes[3] / 2;
    const int N = N_NODES;
    const int* src = edge;
    const int* dst = edge + E;

    auto align256 = [](size_t v) { return (v + 255) & ~(size_t)255; };
    char* ws = (char*)d_ws;
    size_t off = 0;
    int* cnt = (int*)(ws + off);       off += align256((size_t)N * CSTRIDE * 4);   // 3.2 MB
    unsigned short* colb = (unsigned short*)(ws + off);
    off += align256((size_t)N * KCAP * 2);                                         // 9.6 MB
    unsigned short* xb16 = (unsigned short*)(ws + off);
    off += align256((size_t)N * 128 * 2);                                          // 12.8 MB
    unsigned short* b16 = (unsigned short*)(ws + off);
    off += align256((size_t)N * 64 * 2);                                           // 6.4 MB
    unsigned short* W0t = (unsigned short*)(ws + off); off += align256(128 * 128 * 2);
    unsigned short* W1t = (unsigned short*)(ws + off); off += align256(64 * 128 * 2);
    // total ~32.1 MB

    float* out = (float*)d_out;

    // prep: zero padded counters + transpose/cast weights (one launch)
    prep<<<(N * CSTRIDE + 3072 + 255) / 256, 256, 0, stream>>>(W0, W1, cnt, W0t, W1t);

    // fused bucket-CSR build, 3 windowed passes
    const int win = (N + NPASS - 1) / NPASS;
    for (int p = 0; p < NPASS; ++p) {
        int lo = p * win;
        int hi = lo + win; if (hi > N) hi = N;
        build_bucket_win<<<(E + 255) / 256, 256, 0, stream>>>(src, dst, cnt, colb, E, lo, hi);
    }

    // x -> bf16, pre-scaled by rsqrt(deg)
    long n4 = (long)N * 32;
    convert_scale_bf16<<<(int)((n4 + 255) / 256), 256, 0, stream>>>(x, cnt, xb16);

    // fused: gather y1 tile -> MFMA MLP -> b16
    gather_mlp<<<NPAD / 64, 256, 0, stream>>>(cnt, colb, xb16, W0t, W1t, b16);

    // layer 2 gather: out = Â b16
    const int spmm_blocks = (N * 64 + 255) / 256;
    gather_spmm64_bf<<<spmm_blocks, 256, 0, stream>>>(cnt, colb, b16, out);
}